// Round 9
// baseline (1145.171 us; speedup 1.0000x reference)
//
#include <hip/hip_runtime.h>
#include <hip/hip_bf16.h>
#include <math.h>

// NVAR reservoir: out = GELU(poly_feats(x) @ W1 + b1) @ W2 + b2
// R9: DIAGNOSTIC ROUND. Real pipeline = R8 verbatim (passes, ~72us).
// Appended: 4 ablation kernels k_abl<V,REPS> (identical geometry to k_main,
// in-kernel repeats so each exceeds the 44us fills and shows in top-5):
//   V1 x8  : no B global loads (const B)      -> isolates B-stream chain
//   V2 x8  : no MFMA (loads kept live)        -> isolates memory system
//   V3 x8  : no A ds_reads (const A)          -> isolates LDS A-path
//   V4 x16 : const A+B, MFMA only             -> MFMA floor of this shape
// Keep-alives per rule #17; rep-dependent opaque offsets prevent hoisting.

#define NF     51681
#define KPAD   352
#define KCHK   11              // 352/32
#define NFR    21              // 336/16
#define NPAD   (NFR * 16)      // 336
#define MT2    128
#define ATS    768             // A-tile row stride BYTES (multiple of 128)

typedef __attribute__((ext_vector_type(8))) short short8;
typedef __attribute__((ext_vector_type(4))) float f32x4;

#define W1C_BYTES  ((size_t)64 * NF * 2)                // 6,615,168
#define MF_BYTES   ((size_t)64 * KPAD * NPAD * 2)       // 15,138,816
#define HBUF_OFF   (W1C_BYTES + MF_BYTES)
#define AIMG_OFF   (HBUF_OFF + (size_t)1024 * 64 * 4)   // hbuf = 256KB
#define AIMG_SH_PER_TILE 49152                          // 128 rows * 384 shorts
#define DC_OFF     (AIMG_OFF + (size_t)8 * AIMG_SH_PER_TILE * 2)
#define DC_SH_PER_TILE 43008                            // 672 recs * 64 lanes
#define DUMMY_OFF  (DC_OFF + (size_t)8 * DC_SH_PER_TILE * 2)

__device__ __forceinline__ unsigned short f2bf(float x) {
    return __bfloat16_as_ushort(__float2bfloat16(x));
}
__device__ __forceinline__ float bf2f(unsigned short h) {
    union { unsigned u; float f; } v; v.u = ((unsigned)h) << 16; return v.f;
}

// ---- k_t: W1c[e][f] = bf16(W1[f][e]) ----
__global__ void k_t(const float* __restrict__ W1, unsigned short* __restrict__ W1c) {
    __shared__ float t[64 * 65];
    const int tid = threadIdx.x;
    const int f0 = blockIdx.x * 64;
    #pragma unroll
    for (int r = 0; r < 16; ++r) {
        int idx = r * 256 + tid;
        int fi = idx >> 6, e = idx & 63;
        t[fi * 65 + e] = (f0 + fi < NF) ? W1[(size_t)(f0 + fi) * 64 + e] : 0.f;
    }
    __syncthreads();
    #pragma unroll
    for (int r = 0; r < 16; ++r) {
        int idx = r * 256 + tid;
        int e = idx >> 6, fi = idx & 63;
        if (f0 + fi < NF)
            W1c[(size_t)e * NF + f0 + fi] = f2bf(t[fi * 65 + e]);
    }
}

// ---- k_pack: Mfrag in MFMA-fragment order (verified) ----
__global__ void k_pack(const unsigned short* __restrict__ W1c,
                       unsigned short* __restrict__ Mfrag) {
    const int g = blockIdx.x * 256 + threadIdx.x;       // < 946176 exactly
    const int lane = g & 63;
    const int rec = g >> 6;
    const int nf = rec % NFR;
    const int rec2 = rec / NFR;
    const int kc = rec2 % KCHK;
    const int e = rec2 / KCHK;
    const int i = nf * 16 + (lane & 15);
    const int jb = kc * 32 + ((lane >> 4) << 3);
    const unsigned short* wrow = W1c + (size_t)e * NF;

    __attribute__((aligned(16))) unsigned short v[8];
    #pragma unroll
    for (int r = 0; r < 8; ++r) {
        int j = jb + r;
        unsigned short out = 0;
        if (i < 321 && j < 321) {
            if (j == 320) {
                out = (i == 320) ? wrow[0] : wrow[1 + i];
            } else if (i == 320) {
                out = 0;
            } else {
                int p = min(i, j), q = max(i, j);
                int idx = 321 + p * 320 - ((p * (p - 1)) >> 1) + (q - p);
                unsigned short w = wrow[idx];
                out = (i == j) ? w : f2bf(0.5f * bf2f(w));
            }
        }
        v[r] = out;
    }
    *(short8*)(Mfrag + (size_t)g * 8) = *(short8*)v;
}

// ---- k_aprep: per-tile swizzled A-image + fragment-ordered contraction buf ----
__global__ void k_aprep(const float* __restrict__ x, unsigned short* __restrict__ Aimg,
                        unsigned short* __restrict__ DC) {
    __shared__ float xwin[132 * 64];
    const int tile = blockIdx.x >> 2;
    const int qtr  = blockIdx.x & 3;
    const int tid = threadIdx.x;
    const int b = tile >> 2, s0 = (tile & 3) * 128;

    for (int idx = tid; idx < 132 * 64; idx += 256) {
        int r = idx >> 6, ee = idx & 63;
        int s = s0 - 4 + r;
        xwin[idx] = (s >= 0) ? x[((b << 9) + s) * 64 + ee] : 0.f;
    }
    __syncthreads();

    unsigned short* ai = Aimg + (size_t)tile * AIMG_SH_PER_TILE;
    for (int rec = qtr * 1536 + tid; rec < (qtr + 1) * 1536; rec += 256) {
        int t = rec / 48;
        int s16 = (rec - t * 48) * 16;                  // byte slot in row
        int j0 = (s16 ^ ((t & 7) << 4)) >> 1;
        __attribute__((aligned(16))) unsigned short hv[8];
        #pragma unroll
        for (int r = 0; r < 8; ++r) {
            int j = j0 + r;
            float v;
            if (j < 320) { int e5 = j / 5, k = j - e5 * 5; v = xwin[(t + k) * 64 + e5]; }
            else v = (j == 320) ? 1.0f : 0.f;
            hv[r] = f2bf(v);
        }
        *(short8*)(ai + t * 384 + (s16 >> 1)) = *(short8*)hv;
    }

    unsigned short* dc = DC + (size_t)tile * DC_SH_PER_TILE;
    for (int g = qtr * 10752 + tid; g < (qtr + 1) * 10752; g += 256) {
        int lane = g & 63, rec = g >> 6;
        int r = rec & 3;
        int nf = (rec >> 2) % 21;
        int mfw = rec / 84;                             // wm*4 + mf
        int t = mfw * 16 + ((lane >> 4) << 2) + r;
        int i = nf * 16 + (lane & 15);
        float v;
        if (i < 320) { int e5 = i / 5, k = i - e5 * 5; v = xwin[(t + k) * 64 + e5]; }
        else v = (i == 320) ? 1.0f : 0.f;
        dc[g] = f2bf(v);
    }
}

// ---- k_main: per block (e, tile): C = D' M'_e, h = rowdot(C, D') (R8 verbatim) ----
__global__ __launch_bounds__(1024, 4) void k_main(const unsigned short* __restrict__ Aimg,
                                                  const unsigned short* __restrict__ Mfrag,
                                                  const unsigned short* __restrict__ DC,
                                                  float* __restrict__ hbuf) {
    __shared__ unsigned short At[MT2 * (ATS / 2)];
    __shared__ float hpart[2][8][64];

    const int tid = threadIdx.x;
    const int bid = blockIdx.x;
    const int wgid = ((bid & 7) << 6) | (bid >> 3);
    const int e = wgid >> 3;
    const int tile = wgid & 7;
    const int tok0 = tile * MT2;

    {
        const short8* src = (const short8*)(Aimg + (size_t)tile * AIMG_SH_PER_TILE);
        short8* dst = (short8*)At;
        #pragma unroll
        for (int k = 0; k < 6; ++k)
            dst[k * 1024 + tid] = src[k * 1024 + tid];
    }
    __syncthreads();

    const int lane = tid & 63, wv = tid >> 6;
    const int wm = wv >> 3, wn = wv & 7;
    const int nfc = (wn < 5) ? 3 : 2;
    const int nf0 = (wn < 5) ? wn * 3 : 15 + (wn - 5) * 2;
    const unsigned short* Bbase = Mfrag + (size_t)e * (KPAD * NPAD);
    char* Atb = (char*)At;

    f32x4 acc[4][3];
    #pragma unroll
    for (int mf = 0; mf < 4; ++mf)
        #pragma unroll
        for (int q = 0; q < 3; ++q) acc[mf][q] = f32x4{0.f,0.f,0.f,0.f};

    const int arow = wm * 64 + (lane & 15);
    const int aslot = (lane >> 4) << 4;

    short8 B0[3], B1[3];

#define BLD(DST, KCV)                                                              \
    do { if ((KCV) < KCHK) {                                                       \
        _Pragma("unroll")                                                          \
        for (int q = 0; q < 3; ++q)                                                \
            if (q < nfc)                                                           \
                DST[q] = *(const short8*)(Bbase +                                  \
                    ((size_t)(((KCV) * NFR + nf0 + q) * 64 + lane)) * 8);          \
    } } while (0)

#define STEP(KCV, CUR, NXT)                                                        \
    do {                                                                           \
        short8 Af[4];                                                              \
        _Pragma("unroll")                                                          \
        for (int mf = 0; mf < 4; ++mf) {                                           \
            int t = arow + mf * 16;                                                \
            int jb = (KCV) * 64 + aslot;                                           \
            Af[mf] = *(const short8*)(Atb + t * ATS + (jb ^ ((t & 7) << 4)));      \
        }                                                                          \
        BLD(NXT, (KCV) + 1);                                                       \
        _Pragma("unroll")                                                          \
        for (int mf = 0; mf < 4; ++mf) {                                           \
            _Pragma("unroll")                                                      \
            for (int q = 0; q < 3; ++q)                                            \
                if (q < nfc)                                                       \
                    acc[mf][q] = __builtin_amdgcn_mfma_f32_16x16x32_bf16(          \
                        Af[mf], CUR[q], acc[mf][q], 0, 0, 0);                      \
        }                                                                          \
    } while (0)

    BLD(B0, 0);
    STEP(0, B0, B1);
    STEP(1, B1, B0);
    STEP(2, B0, B1);
    STEP(3, B1, B0);
    STEP(4, B0, B1);
    STEP(5, B1, B0);
    STEP(6, B0, B1);
    STEP(7, B1, B0);
    STEP(8, B0, B1);
    STEP(9, B1, B0);
    STEP(10, B0, B1);
#undef STEP
#undef BLD

    float s[4][4];
    #pragma unroll
    for (int mf = 0; mf < 4; ++mf)
        #pragma unroll
        for (int r = 0; r < 4; ++r) s[mf][r] = 0.f;

    const unsigned short* DCb = DC + (size_t)tile * DC_SH_PER_TILE + lane;
    #pragma unroll
    for (int q = 0; q < 3; ++q) {
        if (q < nfc) {
            #pragma unroll
            for (int mf = 0; mf < 4; ++mf)
                #pragma unroll
                for (int r = 0; r < 4; ++r) {
                    unsigned short dv =
                        DCb[((wm * 4 + mf) * 84 + (nf0 + q) * 4 + r) * 64];
                    s[mf][r] += acc[mf][q][r] * bf2f(dv);
                }
        }
    }
    #pragma unroll
    for (int mf = 0; mf < 4; ++mf)
        #pragma unroll
        for (int r = 0; r < 4; ++r) {
            float v = s[mf][r];
            v += __shfl_xor(v, 1);
            v += __shfl_xor(v, 2);
            v += __shfl_xor(v, 4);
            v += __shfl_xor(v, 8);
            s[mf][r] = v;
        }
    if ((lane & 15) == 0) {
        #pragma unroll
        for (int mf = 0; mf < 4; ++mf)
            #pragma unroll
            for (int r = 0; r < 4; ++r)
                hpart[wm][wn][mf * 16 + ((lane >> 4) << 2) + r] = s[mf][r];
    }
    __syncthreads();
    if (tid < 128) {
        int wmx = tid >> 6, tl = tid & 63;
        float v = 0.f;
        #pragma unroll
        for (int w = 0; w < 8; ++w) v += hpart[wmx][w][tl];
        hbuf[(size_t)(tok0 + wmx * 64 + tl) * 64 + e] = v;
    }
}

// ---- k_abl: ablation probe. V1 no-B, V2 no-MFMA, V3 no-A, V4 MFMA-only ----
template<int V, int REPS>
__global__ __launch_bounds__(1024, 4) void k_abl(const unsigned short* __restrict__ Aimg,
                                                 const unsigned short* __restrict__ Mfrag,
                                                 const unsigned short* __restrict__ DC,
                                                 float* __restrict__ dummy) {
    __shared__ unsigned short At[MT2 * (ATS / 2)];
    const int tid = threadIdx.x;
    const int bid = blockIdx.x;
    const int wgid = ((bid & 7) << 6) | (bid >> 3);
    const int e = wgid >> 3;
    const int tile = wgid & 7;

    {
        const short8* src = (const short8*)(Aimg + (size_t)tile * AIMG_SH_PER_TILE);
        short8* dst = (short8*)At;
        #pragma unroll
        for (int k = 0; k < 6; ++k)
            dst[k * 1024 + tid] = src[k * 1024 + tid];
    }
    __syncthreads();

    const int lane = tid & 63, wv = tid >> 6;
    const int wm = wv >> 3, wn = wv & 7;
    const int nfc = (wn < 5) ? 3 : 2;
    const int nf0 = (wn < 5) ? wn * 3 : 15 + (wn - 5) * 2;
    const unsigned short* Bbase = Mfrag + (size_t)e * (KPAD * NPAD);
    char* Atb0 = (char*)At;
    const int arow = wm * 64 + (lane & 15);
    const int aslot = (lane >> 4) << 4;

    int zero = 0;
    asm volatile("" : "+v"(zero));      // opaque 0: defeats hoist/CSE across reps

    short8 cst;
    #pragma unroll
    for (int z = 0; z < 8; ++z) cst[z] = (short)0x3F80;   // bf16 1.0

    float tot = 0.f;

    for (int rep = 0; rep < REPS; ++rep) {
        short8 cstr = cst;
        { f32x4 t0 = *(f32x4*)&cstr; asm volatile("" : "+v"(t0)); cstr = *(short8*)&t0; }
        const unsigned short* Bb = Bbase + (size_t)zero * (rep + 1);
        const char* Atb = Atb0 + (size_t)zero * (rep + 1);

        f32x4 acc[4][3];
        #pragma unroll
        for (int mf = 0; mf < 4; ++mf)
            #pragma unroll
            for (int q = 0; q < 3; ++q) acc[mf][q] = f32x4{0.f,0.f,0.f,0.f};
        if constexpr (V == 2) {        // keep acc opaque so contraction+DC stay live
            #pragma unroll
            for (int mf = 0; mf < 4; ++mf)
                #pragma unroll
                for (int q = 0; q < 3; ++q)
                    asm volatile("" : "+v"(acc[mf][q]));
        }

        short8 B0[3], B1[3];
        if constexpr (V == 1 || V == 4) {
            #pragma unroll
            for (int q = 0; q < 3; ++q) { B0[q] = cstr; B1[q] = cstr; }
        }

#define ABLD(DST, KCV)                                                             \
    do { if constexpr (V != 1 && V != 4) { if ((KCV) < KCHK) {                     \
        _Pragma("unroll")                                                          \
        for (int q = 0; q < 3; ++q)                                                \
            if (q < nfc)                                                           \
                DST[q] = *(const short8*)(Bb +                                     \
                    ((size_t)(((KCV) * NFR + nf0 + q) * 64 + lane)) * 8);          \
    } } } while (0)

#define ASTEP(KCV, CUR, NXT)                                                       \
    do {                                                                           \
        short8 Af[4];                                                              \
        if constexpr (V == 3 || V == 4) {                                          \
            _Pragma("unroll")                                                      \
            for (int mf = 0; mf < 4; ++mf) Af[mf] = cstr;                          \
        } else {                                                                   \
            _Pragma("unroll")                                                      \
            for (int mf = 0; mf < 4; ++mf) {                                       \
                int t = arow + mf * 16;                                            \
                int jb = (KCV) * 64 + aslot;                                       \
                Af[mf] = *(const short8*)(Atb + t * ATS + (jb ^ ((t & 7) << 4)));  \
            }                                                                      \
        }                                                                          \
        ABLD(NXT, (KCV) + 1);                                                      \
        if constexpr (V == 2) {                                                    \
            _Pragma("unroll")                                                      \
            for (int mf = 0; mf < 4; ++mf)                                         \
                asm volatile("" :: "v"(*(const f32x4*)&Af[mf]));                   \
            _Pragma("unroll")                                                      \
            for (int q = 0; q < 3; ++q)                                            \
                asm volatile("" :: "v"(*(const f32x4*)&CUR[q]));                   \
        } else {                                                                   \
            _Pragma("unroll")                                                      \
            for (int mf = 0; mf < 4; ++mf) {                                       \
                _Pragma("unroll")                                                  \
                for (int q = 0; q < 3; ++q)                                        \
                    if (q < nfc)                                                   \
                        acc[mf][q] = __builtin_amdgcn_mfma_f32_16x16x32_bf16(      \
                            Af[mf], CUR[q], acc[mf][q], 0, 0, 0);                  \
            }                                                                      \
        }                                                                          \
    } while (0)

        ABLD(B0, 0);
        ASTEP(0, B0, B1);
        ASTEP(1, B1, B0);
        ASTEP(2, B0, B1);
        ASTEP(3, B1, B0);
        ASTEP(4, B0, B1);
        ASTEP(5, B1, B0);
        ASTEP(6, B0, B1);
        ASTEP(7, B1, B0);
        ASTEP(8, B0, B1);
        ASTEP(9, B1, B0);
        ASTEP(10, B0, B1);
#undef ASTEP
#undef ABLD

        if constexpr (V != 4) {
            float s[4][4];
            #pragma unroll
            for (int mf = 0; mf < 4; ++mf)
                #pragma unroll
                for (int r = 0; r < 4; ++r) s[mf][r] = 0.f;
            const unsigned short* DCr = DC + (size_t)tile * DC_SH_PER_TILE + lane
                                        + (size_t)zero * (rep + 1);
            #pragma unroll
            for (int q = 0; q < 3; ++q) {
                if (q < nfc) {
                    #pragma unroll
                    for (int mf = 0; mf < 4; ++mf)
                        #pragma unroll
                        for (int r = 0; r < 4; ++r) {
                            unsigned short dv =
                                DCr[((wm * 4 + mf) * 84 + (nf0 + q) * 4 + r) * 64];
                            s[mf][r] += acc[mf][q][r] * bf2f(dv);
                        }
                }
            }
            #pragma unroll
            for (int mf = 0; mf < 4; ++mf)
                #pragma unroll
                for (int r = 0; r < 4; ++r) {
                    float v = s[mf][r];
                    v += __shfl_xor(v, 1);
                    v += __shfl_xor(v, 2);
                    v += __shfl_xor(v, 4);
                    v += __shfl_xor(v, 8);
                    tot += v;
                }
        } else {
            #pragma unroll
            for (int mf = 0; mf < 4; ++mf)
                #pragma unroll
                for (int q = 0; q < 3; ++q)
                    #pragma unroll
                    for (int r = 0; r < 4; ++r) tot += acc[mf][q][r];
        }
    }
    dummy[(size_t)bid * 1024 + tid] = tot;
}

// ---- epilogue: out = GELU(hbuf + b1) @ W2 + b2 ----
__global__ void k_epi(const float* __restrict__ hbuf, const float* __restrict__ b1,
                      const float* __restrict__ W2, const float* __restrict__ b2,
                      float* __restrict__ out) {
    __shared__ float h[4 * 64];
    int tid = threadIdx.x;
    int t = tid >> 6, e = tid & 63;
    int token = blockIdx.x * 4 + t;
    float pre = hbuf[token * 64 + e] + b1[e];
    float hv = 0.5f * pre * (1.0f + erff(pre * 0.70710678118654752f));  // exact GELU
    h[t * 64 + e] = hv;
    __syncthreads();
    float s = b2[e];
    #pragma unroll 8
    for (int ee = 0; ee < 64; ++ee)
        s += h[t * 64 + ee] * W2[ee * 64 + e];
    out[token * 64 + e] = s;
}

extern "C" void kernel_launch(void* const* d_in, const int* in_sizes, int n_in,
                              void* d_out, int out_size, void* d_ws, size_t ws_size,
                              hipStream_t stream) {
    const float* x  = (const float*)d_in[0];
    const float* W1 = (const float*)d_in[1];
    const float* b1 = (const float*)d_in[2];
    const float* W2 = (const float*)d_in[3];
    const float* b2 = (const float*)d_in[4];
    float* out = (float*)d_out;

    unsigned short* W1c   = (unsigned short*)d_ws;
    unsigned short* Mfrag = (unsigned short*)((char*)d_ws + W1C_BYTES);
    float* hbuf           = (float*)((char*)d_ws + HBUF_OFF);
    unsigned short* Aimg  = (unsigned short*)((char*)d_ws + AIMG_OFF);
    unsigned short* DC    = (unsigned short*)((char*)d_ws + DC_OFF);
    float* dummy          = (float*)((char*)d_ws + DUMMY_OFF);

    k_t<<<(NF + 63) / 64, 256, 0, stream>>>(W1, W1c);
    k_pack<<<3696, 256, 0, stream>>>(W1c, Mfrag);
    k_aprep<<<32, 256, 0, stream>>>(x, Aimg, DC);
    k_main<<<512, 1024, 0, stream>>>(Aimg, Mfrag, DC, hbuf);
    k_epi<<<256, 256, 0, stream>>>(hbuf, b1, W2, b2, out);

    // ---- ablation probes (do not touch hbuf/out) ----
    k_abl<1, 8><<<512, 1024, 0, stream>>>(Aimg, Mfrag, DC, dummy);   // no B-loads
    k_abl<2, 8><<<512, 1024, 0, stream>>>(Aimg, Mfrag, DC, dummy);   // no MFMA
    k_abl<3, 8><<<512, 1024, 0, stream>>>(Aimg, Mfrag, DC, dummy);   // no A-reads
    k_abl<4, 16><<<512, 1024, 0, stream>>>(Aimg, Mfrag, DC, dummy);  // MFMA floor
}

// Round 10
// 68.516 us; speedup vs baseline: 16.7139x; 16.7139x over previous
//
#include <hip/hip_runtime.h>
#include <hip/hip_bf16.h>
#include <math.h>

// NVAR reservoir: out = GELU(poly_feats(x) @ W1 + b1) @ W2 + b2
// B=2 S=512 E=64 DELAY=5 -> L=320, F=51681, tokens=1024
//
// R10: bilinear formulation (R7 base, verified). Key change: BRANCH-FREE
// kc-loop. R9's ablation showed memory chains alone ~= whole kernel and
// MFMA ~free; the per-MFMA `if (q < nfc)` uniform branches (12/step) were
// blocking load/MFMA interleave. NPAD 336->384 (NFR 24) makes nfc=3 for
// all 8 wn-waves -> straight-line loop. Also: 3-deep B prefetch, B-loads
// issued at step top, s_setprio around MFMA cluster.

#define NF     51681
#define KPAD   352
#define KCHK   11              // 352/32
#define NFR    24              // 384/16  (padded: frags 21..23 are zero)
#define NPAD   (NFR * 16)      // 384
#define MT2    128
#define ATS    768             // A-tile row stride BYTES (multiple of 128)

typedef __attribute__((ext_vector_type(8))) short short8;
typedef __attribute__((ext_vector_type(4))) float f32x4;

#define W1C_BYTES  ((size_t)64 * NF * 2)                // 6,615,168
#define MF_BYTES   ((size_t)64 * KPAD * NPAD * 2)       // 17,301,504
#define HBUF_OFF   (W1C_BYTES + MF_BYTES)

__device__ __forceinline__ unsigned short f2bf(float x) {
    return __bfloat16_as_ushort(__float2bfloat16(x));
}
__device__ __forceinline__ float bf2f(unsigned short h) {
    union { unsigned u; float f; } v; v.u = ((unsigned)h) << 16; return v.f;
}

// ---- k_t: W1c[e][f] = bf16(W1[f][e]) ----
__global__ void k_t(const float* __restrict__ W1, unsigned short* __restrict__ W1c) {
    __shared__ float t[64 * 65];
    const int tid = threadIdx.x;
    const int f0 = blockIdx.x * 64;
    #pragma unroll
    for (int r = 0; r < 16; ++r) {
        int idx = r * 256 + tid;
        int fi = idx >> 6, e = idx & 63;
        t[fi * 65 + e] = (f0 + fi < NF) ? W1[(size_t)(f0 + fi) * 64 + e] : 0.f;
    }
    __syncthreads();
    #pragma unroll
    for (int r = 0; r < 16; ++r) {
        int idx = r * 256 + tid;
        int e = idx >> 6, fi = idx & 63;
        if (f0 + fi < NF)
            W1c[(size_t)e * NF + f0 + fi] = f2bf(t[fi * 65 + e]);
    }
}

// ---- k_pack: Mfrag in MFMA-fragment order (padded cols 336..383 -> 0) ----
// short index = (((e*11 + kc)*24 + nf)*64 + lane)*8 + r
// j = kc*32 + (lane>>4)*8 + r (K index), i = nf*16 + (lane&15) (N index)
__global__ void k_pack(const unsigned short* __restrict__ W1c,
                       unsigned short* __restrict__ Mfrag) {
    const int g = blockIdx.x * 256 + threadIdx.x;       // < 1,081,344 exactly
    const int lane = g & 63;
    const int rec = g >> 6;                             // < 16896 = 64*11*24
    const int nf = rec % NFR;
    const int rec2 = rec / NFR;
    const int kc = rec2 % KCHK;
    const int e = rec2 / KCHK;
    const int i = nf * 16 + (lane & 15);
    const int jb = kc * 32 + ((lane >> 4) << 3);
    const unsigned short* wrow = W1c + (size_t)e * NF;

    __attribute__((aligned(16))) unsigned short v[8];
    #pragma unroll
    for (int r = 0; r < 8; ++r) {
        int j = jb + r;
        unsigned short out = 0;
        if (i < 321 && j < 321) {
            if (j == 320) {
                out = (i == 320) ? wrow[0] : wrow[1 + i];
            } else if (i == 320) {
                out = 0;
            } else {
                int p = min(i, j), q = max(i, j);
                int idx = 321 + p * 320 - ((p * (p - 1)) >> 1) + (q - p);
                unsigned short w = wrow[idx];
                out = (i == j) ? w : f2bf(0.5f * bf2f(w));
            }
        }
        v[r] = out;
    }
    *(short8*)(Mfrag + (size_t)g * 8) = *(short8*)v;
}

// ---- k_main: per block (e, tile of 128 tokens): C = D' M'_e, h = rowdot(C, D') ----
__global__ __launch_bounds__(1024, 4) void k_main(const float* __restrict__ x,
                                                  const unsigned short* __restrict__ Mfrag,
                                                  float* __restrict__ hbuf) {
    __shared__ unsigned short At[MT2 * (ATS / 2)];  // swizzled bf16, row 768B
    __shared__ float xwin[132 * 64];
    __shared__ float hpart[2][8][64];

    const int tid = threadIdx.x;
    const int e = blockIdx.x;                   // bid%8 = e%8 -> tiles of an e share XCD
    const int bx = blockIdx.y;                  // 0..7
    const int tok0 = bx * MT2;
    const int b = bx >> 2, s0 = (bx & 3) * MT2;

    // stage x window: rows r in [0,132), s = s0-4+r
    for (int idx = tid; idx < 132 * 64; idx += 1024) {
        int r = idx >> 6, ee = idx & 63;
        int s = s0 - 4 + r;
        xwin[idx] = (s >= 0) ? x[((b << 9) + s) * 64 + ee] : 0.f;
    }
    __syncthreads();

    // build A-tile: At[t][j] = bf16(d'[t][j]); rows now FULL 384 shorts (pad zeroed)
    char* Atb = (char*)At;
    for (int rec = tid; rec < MT2 * 48; rec += 1024) {   // 48 = 384/8
        int t = rec / 48, jr = rec - t * 48;
        int j0 = jr * 8;
        __attribute__((aligned(16))) unsigned short hv[8];
        #pragma unroll
        for (int r = 0; r < 8; ++r) {
            int j = j0 + r;
            float v;
            if (j < 320) { int e5 = j / 5, k = j - e5 * 5; v = xwin[(t + k) * 64 + e5]; }
            else v = (j == 320) ? 1.0f : 0.f;
            hv[r] = f2bf(v);
        }
        *(short8*)(Atb + t * ATS + ((j0 * 2) ^ ((t & 7) << 4))) = *(short8*)hv;
    }
    __syncthreads();

    const int lane = tid & 63, wv = tid >> 6;   // 16 waves
    const int wm = wv >> 3, wn = wv & 7;        // M-half, N-slice
    const int nf0 = wn * 3;                     // UNIFORM: every wave owns 3 frags
    const unsigned short* Bbase = Mfrag + (size_t)e * (KPAD * NPAD);

    f32x4 acc[4][3];
    #pragma unroll
    for (int mf = 0; mf < 4; ++mf)
        #pragma unroll
        for (int q = 0; q < 3; ++q) acc[mf][q] = f32x4{0.f,0.f,0.f,0.f};

    const int arow = wm * 64 + (lane & 15);
    const int aslot = (lane >> 4) << 4;

    short8 B0[3], B1[3], B2[3];

#define BLD(DST, KCV)                                                              \
    do { if ((KCV) < KCHK) {                                                       \
        _Pragma("unroll")                                                          \
        for (int q = 0; q < 3; ++q)                                                \
            DST[q] = *(const short8*)(Bbase +                                      \
                ((size_t)(((KCV) * NFR + nf0 + q) * 64 + lane)) * 8);              \
    } } while (0)

#define STEP(KCV, CUR, NXT)                                                        \
    do {                                                                           \
        BLD(NXT, (KCV) + 2);   /* issue next-next B first (T3 ordering) */         \
        short8 Af[4];                                                              \
        _Pragma("unroll")                                                          \
        for (int mf = 0; mf < 4; ++mf) {                                           \
            int t = arow + mf * 16;                                                \
            int jb = (KCV) * 64 + aslot;                                           \
            Af[mf] = *(const short8*)(Atb + t * ATS + (jb ^ ((t & 7) << 4)));      \
        }                                                                          \
        __builtin_amdgcn_s_setprio(1);                                             \
        _Pragma("unroll")                                                          \
        for (int mf = 0; mf < 4; ++mf) {                                           \
            _Pragma("unroll")                                                      \
            for (int q = 0; q < 3; ++q)                                            \
                acc[mf][q] = __builtin_amdgcn_mfma_f32_16x16x32_bf16(              \
                    Af[mf], CUR[q], acc[mf][q], 0, 0, 0);                          \
        }                                                                          \
        __builtin_amdgcn_s_setprio(0);                                             \
    } while (0)

    BLD(B0, 0);
    BLD(B1, 1);
    STEP(0, B0, B2);
    STEP(1, B1, B0);
    STEP(2, B2, B1);
    STEP(3, B0, B2);
    STEP(4, B1, B0);
    STEP(5, B2, B1);
    STEP(6, B0, B2);
    STEP(7, B1, B0);
    STEP(8, B2, B1);
    STEP(9, B0, B2);
    STEP(10, B1, B0);
#undef STEP
#undef BLD

    // contraction: s[mf][r] = sum_i C[t][i] * D'[t][i] over this wave's i-slice
    float s[4][4];
    #pragma unroll
    for (int mf = 0; mf < 4; ++mf)
        #pragma unroll
        for (int r = 0; r < 4; ++r) s[mf][r] = 0.f;

    #pragma unroll
    for (int q = 0; q < 3; ++q) {
        int i2 = ((nf0 + q) * 16 + (lane & 15)) * 2;
        #pragma unroll
        for (int mf = 0; mf < 4; ++mf)
            #pragma unroll
            for (int r = 0; r < 4; ++r) {
                int t = wm * 64 + mf * 16 + ((lane >> 4) << 2) + r;
                unsigned short dv = *(const unsigned short*)(Atb + t * ATS + (i2 ^ ((t & 7) << 4)));
                s[mf][r] += acc[mf][q][r] * bf2f(dv);
            }
    }
    // reduce across the 16 lanes of each i-column group
    #pragma unroll
    for (int mf = 0; mf < 4; ++mf)
        #pragma unroll
        for (int r = 0; r < 4; ++r) {
            float v = s[mf][r];
            v += __shfl_xor(v, 1);
            v += __shfl_xor(v, 2);
            v += __shfl_xor(v, 4);
            v += __shfl_xor(v, 8);
            s[mf][r] = v;
        }
    if ((lane & 15) == 0) {
        #pragma unroll
        for (int mf = 0; mf < 4; ++mf)
            #pragma unroll
            for (int r = 0; r < 4; ++r)
                hpart[wm][wn][mf * 16 + ((lane >> 4) << 2) + r] = s[mf][r];
    }
    __syncthreads();
    if (tid < 128) {
        int wmx = tid >> 6, tl = tid & 63;
        float v = 0.f;
        #pragma unroll
        for (int w = 0; w < 8; ++w) v += hpart[wmx][w][tl];
        hbuf[(size_t)(tok0 + wmx * 64 + tl) * 64 + e] = v;
    }
}

// ---- epilogue: out = GELU(hbuf + b1) @ W2 + b2 ----
__global__ void k_epi(const float* __restrict__ hbuf, const float* __restrict__ b1,
                      const float* __restrict__ W2, const float* __restrict__ b2,
                      float* __restrict__ out) {
    __shared__ float h[4 * 64];
    int tid = threadIdx.x;
    int t = tid >> 6, e = tid & 63;
    int token = blockIdx.x * 4 + t;
    float pre = hbuf[token * 64 + e] + b1[e];
    float hv = 0.5f * pre * (1.0f + erff(pre * 0.70710678118654752f));  // exact GELU
    h[t * 64 + e] = hv;
    __syncthreads();
    float s = b2[e];
    #pragma unroll 8
    for (int ee = 0; ee < 64; ++ee)
        s += h[t * 64 + ee] * W2[ee * 64 + e];
    out[token * 64 + e] = s;
}

extern "C" void kernel_launch(void* const* d_in, const int* in_sizes, int n_in,
                              void* d_out, int out_size, void* d_ws, size_t ws_size,
                              hipStream_t stream) {
    const float* x  = (const float*)d_in[0];
    const float* W1 = (const float*)d_in[1];
    const float* b1 = (const float*)d_in[2];
    const float* W2 = (const float*)d_in[3];
    const float* b2 = (const float*)d_in[4];
    float* out = (float*)d_out;

    unsigned short* W1c   = (unsigned short*)d_ws;
    unsigned short* Mfrag = (unsigned short*)((char*)d_ws + W1C_BYTES);
    float* hbuf           = (float*)((char*)d_ws + HBUF_OFF);

    k_t<<<(NF + 63) / 64, 256, 0, stream>>>(W1, W1c);
    k_pack<<<4224, 256, 0, stream>>>(W1c, Mfrag);          // 1,081,344 threads exactly
    k_main<<<dim3(64, 8), 1024, 0, stream>>>(x, Mfrag, hbuf);
    k_epi<<<256, 256, 0, stream>>>(hbuf, b1, W2, b2, out);
}

// Round 11
// 65.253 us; speedup vs baseline: 17.5497x; 1.0500x over previous
//
#include <hip/hip_runtime.h>
#include <hip/hip_bf16.h>
#include <math.h>

// NVAR reservoir: out = GELU(poly_feats(x) @ W1 + b1) @ W2 + b2
// B=2 S=512 E=64 DELAY=5 -> L=320, F=51681, tokens=1024
//
// R11: bilinear formulation. One grid round: 256 blocks (1/CU exactly),
// each block = (tile of 128 tokens) x (2 e-values): prologue once,
// kc-loop+contraction twice. xw back to [e][r] (conflict-free, R1-R4
// proven); contraction reads d straight from xw (no At re-read).
// B is now UPPER-TRIANGULAR full-w (no 0.5 halving; k_pack reads halved).

#define NF     51681
#define KPAD   352
#define KCHK   11              // 352/32
#define NFR    24              // 384/16 (frags 21..23 zero)
#define NPAD   (NFR * 16)      // 384
#define MT2    128
#define ATS    768             // At row stride BYTES (multiple of 128)
#define XWS    133             // xw row stride (floats)

typedef __attribute__((ext_vector_type(8))) short short8;
typedef __attribute__((ext_vector_type(4))) float f32x4;

#define W1C_BYTES  ((size_t)64 * NF * 2)                // 6,615,168
#define MF_BYTES   ((size_t)64 * KPAD * NPAD * 2)       // 17,301,504
#define HBUF_OFF   (W1C_BYTES + MF_BYTES)

__device__ __forceinline__ unsigned short f2bf(float x) {
    return __bfloat16_as_ushort(__float2bfloat16(x));
}
__device__ __forceinline__ float bf2f(unsigned short h) {
    union { unsigned u; float f; } v; v.u = ((unsigned)h) << 16; return v.f;
}

// ---- k_t: W1c[e][f] = bf16(W1[f][e]) ----
__global__ void k_t(const float* __restrict__ W1, unsigned short* __restrict__ W1c) {
    __shared__ float t[64 * 65];
    const int tid = threadIdx.x;
    const int f0 = blockIdx.x * 64;
    #pragma unroll
    for (int r = 0; r < 16; ++r) {
        int idx = r * 256 + tid;
        int fi = idx >> 6, e = idx & 63;
        t[fi * 65 + e] = (f0 + fi < NF) ? W1[(size_t)(f0 + fi) * 64 + e] : 0.f;
    }
    __syncthreads();
    #pragma unroll
    for (int r = 0; r < 16; ++r) {
        int idx = r * 256 + tid;
        int e = idx >> 6, fi = idx & 63;
        if (f0 + fi < NF)
            W1c[(size_t)e * NF + f0 + fi] = f2bf(t[fi * 65 + e]);
    }
}

// ---- k_pack: Mfrag = UPPER-TRIANGULAR M'_e in MFMA-fragment order ----
// short index = (((e*11 + kc)*24 + nf)*64 + lane)*8 + r
// j = kc*32 + (lane>>4)*8 + r (K index), i = nf*16 + (lane&15) (N index)
// out = w[i,j] if i<=j<=320 (j==320 col = linear terms / const), else 0.
__global__ void k_pack(const unsigned short* __restrict__ W1c,
                       unsigned short* __restrict__ Mfrag) {
    const int g = blockIdx.x * 256 + threadIdx.x;       // < 1,081,344 exactly
    const int lane = g & 63;
    const int rec = g >> 6;                             // < 16896 = 64*11*24
    const int nf = rec % NFR;
    const int rec2 = rec / NFR;
    const int kc = rec2 % KCHK;
    const int e = rec2 / KCHK;
    const int i = nf * 16 + (lane & 15);
    const int jb = kc * 32 + ((lane >> 4) << 3);
    const unsigned short* wrow = W1c + (size_t)e * NF;

    __attribute__((aligned(16))) unsigned short v[8];
    #pragma unroll
    for (int r = 0; r < 8; ++r) {
        int j = jb + r;
        unsigned short out = 0;
        if (i <= j && j <= 320) {
            if (j == 320) {
                out = (i == 320) ? wrow[0] : wrow[1 + i];
            } else {
                int idx = 321 + i * 320 - ((i * (i - 1)) >> 1) + (j - i);
                out = wrow[idx];
            }
        }
        v[r] = out;
    }
    *(short8*)(Mfrag + (size_t)g * 8) = *(short8*)v;
}

// ---- k_main: block = (tile, e-pair). C = D' U_e, h = rowdot(C, D') ----
__global__ __launch_bounds__(1024, 1) void k_main(const float* __restrict__ x,
                                                  const unsigned short* __restrict__ Mfrag,
                                                  float* __restrict__ hbuf) {
    __shared__ unsigned short At[MT2 * (ATS / 2)];  // 96KB swizzled bf16
    __shared__ float xw[64 * XWS];                  // [e][r], stride 133
    __shared__ float hpart[2][8][64];

    const int tid = threadIdx.x;
    const int bid = blockIdx.x;                 // 256 blocks = 1/CU, single round
    const int tile = bid >> 5;                  // 0..7
    const int ep = bid & 31;                    // XCD = ep%8 -> 8 e per XCD (L2-fit)
    const int e0 = ep * 2;
    const int tok0 = tile * MT2;
    const int b = tile >> 2, s0 = (tile & 3) * MT2;

    // stage xw[e][r] = x[b][s0-4+r][e], r in [0,132)
    for (int idx = tid; idx < 132 * 64; idx += 1024) {
        int r = idx >> 6, ee = idx & 63;
        int s = s0 - 4 + r;
        xw[ee * XWS + r] = (s >= 0) ? x[((b << 9) + s) * 64 + ee] : 0.f;
    }
    __syncthreads();

    // build A-tile: At[t][j] = bf16(d'[t][j]), rows 384 shorts, swizzled
    char* Atb = (char*)At;
    for (int rec = tid; rec < MT2 * 48; rec += 1024) {
        int t = rec / 48, jr = rec - t * 48;
        int j0 = jr * 8;
        __attribute__((aligned(16))) unsigned short hv[8];
        #pragma unroll
        for (int r = 0; r < 8; ++r) {
            int j = j0 + r;
            float v;
            if (j < 320) { int e5 = j / 5, k = j - e5 * 5; v = xw[e5 * XWS + t + k]; }
            else v = (j == 320) ? 1.0f : 0.f;
            hv[r] = f2bf(v);
        }
        *(short8*)(Atb + t * ATS + ((j0 * 2) ^ ((t & 7) << 4))) = *(short8*)hv;
    }
    __syncthreads();

    const int lane = tid & 63, wv = tid >> 6;   // 16 waves
    const int wm = wv >> 3, wn = wv & 7;        // M-half, N-slice
    const int nf0 = wn * 3;                     // uniform 3 frags per wave
    const int arow = wm * 64 + (lane & 15);
    const int aslot = (lane >> 4) << 4;

    // contraction d-operand bases (i per q, read from xw)
    int ibase[3]; float isel1[3], isel0[3];
    #pragma unroll
    for (int q = 0; q < 3; ++q) {
        int i = (nf0 + q) * 16 + (lane & 15);
        int ic = (i < 320) ? i : 0;
        ibase[q] = (ic / 5) * XWS + (ic % 5);
        isel1[q] = (i < 320) ? 1.f : 0.f;       // use xw value?
        isel0[q] = (i == 320) ? 1.f : 0.f;      // else constant 1 (i==320) or 0
    }

    #pragma unroll
    for (int eo = 0; eo < 2; ++eo) {
        const unsigned short* Bbase = Mfrag + (size_t)(e0 + eo) * (KPAD * NPAD);

        f32x4 acc[4][3];
        #pragma unroll
        for (int mf = 0; mf < 4; ++mf)
            #pragma unroll
            for (int q = 0; q < 3; ++q) acc[mf][q] = f32x4{0.f,0.f,0.f,0.f};

        short8 B0[3], B1[3], B2[3];

#define BLD(DST, KCV)                                                              \
    do { if ((KCV) < KCHK) {                                                       \
        _Pragma("unroll")                                                          \
        for (int q = 0; q < 3; ++q)                                                \
            DST[q] = *(const short8*)(Bbase +                                      \
                ((size_t)(((KCV) * NFR + nf0 + q) * 64 + lane)) * 8);              \
    } } while (0)

#define STEP(KCV, CUR, NXT)                                                        \
    do {                                                                           \
        BLD(NXT, (KCV) + 2);                                                       \
        short8 Af[4];                                                              \
        _Pragma("unroll")                                                          \
        for (int mf = 0; mf < 4; ++mf) {                                           \
            int t = arow + mf * 16;                                                \
            int jb = (KCV) * 64 + aslot;                                           \
            Af[mf] = *(const short8*)(Atb + t * ATS + (jb ^ ((t & 7) << 4)));      \
        }                                                                          \
        __builtin_amdgcn_s_setprio(1);                                             \
        _Pragma("unroll")                                                          \
        for (int mf = 0; mf < 4; ++mf) {                                           \
            _Pragma("unroll")                                                      \
            for (int q = 0; q < 3; ++q)                                            \
                acc[mf][q] = __builtin_amdgcn_mfma_f32_16x16x32_bf16(              \
                    Af[mf], CUR[q], acc[mf][q], 0, 0, 0);                          \
        }                                                                          \
        __builtin_amdgcn_s_setprio(0);                                             \
    } while (0)

        BLD(B0, 0);
        BLD(B1, 1);
        STEP(0, B0, B2);
        STEP(1, B1, B0);
        STEP(2, B2, B1);
        STEP(3, B0, B2);
        STEP(4, B1, B0);
        STEP(5, B2, B1);
        STEP(6, B0, B2);
        STEP(7, B1, B0);
        STEP(8, B2, B1);
        STEP(9, B0, B2);
        STEP(10, B1, B0);
#undef STEP
#undef BLD

        // contraction: s[mf][r] = sum_i C[t][i]*d'[t][i]; d' read from xw
        float s[4][4];
        #pragma unroll
        for (int mf = 0; mf < 4; ++mf)
            #pragma unroll
            for (int r = 0; r < 4; ++r) s[mf][r] = 0.f;

        #pragma unroll
        for (int q = 0; q < 3; ++q) {
            #pragma unroll
            for (int mf = 0; mf < 4; ++mf)
                #pragma unroll
                for (int r = 0; r < 4; ++r) {
                    int t = wm * 64 + mf * 16 + ((lane >> 4) << 2) + r;
                    float dv = isel1[q] * xw[ibase[q] + t] + isel0[q];
                    s[mf][r] += acc[mf][q][r] * dv;
                }
        }
        #pragma unroll
        for (int mf = 0; mf < 4; ++mf)
            #pragma unroll
            for (int r = 0; r < 4; ++r) {
                float v = s[mf][r];
                v += __shfl_xor(v, 1);
                v += __shfl_xor(v, 2);
                v += __shfl_xor(v, 4);
                v += __shfl_xor(v, 8);
                s[mf][r] = v;
            }
        if ((lane & 15) == 0) {
            #pragma unroll
            for (int mf = 0; mf < 4; ++mf)
                #pragma unroll
                for (int r = 0; r < 4; ++r)
                    hpart[wm][wn][mf * 16 + ((lane >> 4) << 2) + r] = s[mf][r];
        }
        __syncthreads();
        if (tid < 128) {
            int wmx = tid >> 6, tl = tid & 63;
            float v = 0.f;
            #pragma unroll
            for (int w = 0; w < 8; ++w) v += hpart[wmx][w][tl];
            hbuf[(size_t)(tok0 + wmx * 64 + tl) * 64 + (e0 + eo)] = v;
        }
        __syncthreads();   // hpart readers done before next eo overwrites
    }
}

// ---- epilogue: out = GELU(hbuf + b1) @ W2 + b2 ----
__global__ void k_epi(const float* __restrict__ hbuf, const float* __restrict__ b1,
                      const float* __restrict__ W2, const float* __restrict__ b2,
                      float* __restrict__ out) {
    __shared__ float h[4 * 64];
    int tid = threadIdx.x;
    int t = tid >> 6, e = tid & 63;
    int token = blockIdx.x * 4 + t;
    float pre = hbuf[token * 64 + e] + b1[e];
    float hv = 0.5f * pre * (1.0f + erff(pre * 0.70710678118654752f));  // exact GELU
    h[t * 64 + e] = hv;
    __syncthreads();
    float s = b2[e];
    #pragma unroll 8
    for (int ee = 0; ee < 64; ++ee)
        s += h[t * 64 + ee] * W2[ee * 64 + e];
    out[token * 64 + e] = s;
}

extern "C" void kernel_launch(void* const* d_in, const int* in_sizes, int n_in,
                              void* d_out, int out_size, void* d_ws, size_t ws_size,
                              hipStream_t stream) {
    const float* x  = (const float*)d_in[0];
    const float* W1 = (const float*)d_in[1];
    const float* b1 = (const float*)d_in[2];
    const float* W2 = (const float*)d_in[3];
    const float* b2 = (const float*)d_in[4];
    float* out = (float*)d_out;

    unsigned short* W1c   = (unsigned short*)d_ws;
    unsigned short* Mfrag = (unsigned short*)((char*)d_ws + W1C_BYTES);
    float* hbuf           = (float*)((char*)d_ws + HBUF_OFF);

    k_t<<<(NF + 63) / 64, 256, 0, stream>>>(W1, W1c);
    k_pack<<<4224, 256, 0, stream>>>(W1c, Mfrag);          // 1,081,344 threads
    k_main<<<256, 1024, 0, stream>>>(x, Mfrag, hbuf);
    k_epi<<<256, 256, 0, stream>>>(hbuf, b1, W2, b2, out);
}

// Round 12
// 54.627 us; speedup vs baseline: 20.9635x; 1.1945x over previous
//
#include <hip/hip_runtime.h>
#include <hip/hip_bf16.h>
#include <math.h>

// NVAR reservoir: out = GELU(poly_feats(x) @ W1 + b1) @ W2 + b2
// B=2 S=512 E=64 DELAY=5 -> L=320, F=51681, tokens=1024
//
// R12: identical math/layout to R11 (verified, 65us). ONLY change: code
// footprint. R6-R11 all fully unrolled (~2.5K inst ~20KB), marginal vs
// the 32KB L1I, no loop barriers -> waves drift -> I$ thrash = the ~7x
// gap no pipe counter shows. Here: eo-loop rolled, kc-loop runtime with
// 2 steps/iter ping-pong prefetch, prologue rolled. ~4-5KB body.

#define NF     51681
#define KPAD   352
#define KCHK   11              // 352/32
#define NFR    24              // 384/16 (frags 21..23 zero)
#define NPAD   (NFR * 16)      // 384
#define MT2    128
#define ATS    768             // At row stride BYTES (multiple of 128)
#define XWS    133             // xw row stride (floats)

typedef __attribute__((ext_vector_type(8))) short short8;
typedef __attribute__((ext_vector_type(4))) float f32x4;

#define W1C_BYTES  ((size_t)64 * NF * 2)                // 6,615,168
#define MF_BYTES   ((size_t)64 * KPAD * NPAD * 2)       // 17,301,504
#define HBUF_OFF   (W1C_BYTES + MF_BYTES)

__device__ __forceinline__ unsigned short f2bf(float x) {
    return __bfloat16_as_ushort(__float2bfloat16(x));
}
__device__ __forceinline__ float bf2f(unsigned short h) {
    union { unsigned u; float f; } v; v.u = ((unsigned)h) << 16; return v.f;
}

// ---- k_t: W1c[e][f] = bf16(W1[f][e]) ----
__global__ void k_t(const float* __restrict__ W1, unsigned short* __restrict__ W1c) {
    __shared__ float t[64 * 65];
    const int tid = threadIdx.x;
    const int f0 = blockIdx.x * 64;
    #pragma unroll 1
    for (int r = 0; r < 16; ++r) {
        int idx = r * 256 + tid;
        int fi = idx >> 6, e = idx & 63;
        t[fi * 65 + e] = (f0 + fi < NF) ? W1[(size_t)(f0 + fi) * 64 + e] : 0.f;
    }
    __syncthreads();
    #pragma unroll 1
    for (int r = 0; r < 16; ++r) {
        int idx = r * 256 + tid;
        int e = idx >> 6, fi = idx & 63;
        if (f0 + fi < NF)
            W1c[(size_t)e * NF + f0 + fi] = f2bf(t[fi * 65 + e]);
    }
}

// ---- k_pack: Mfrag = UPPER-TRIANGULAR M'_e in MFMA-fragment order ----
// short index = (((e*11 + kc)*24 + nf)*64 + lane)*8 + r
// j = kc*32 + (lane>>4)*8 + r (K index), i = nf*16 + (lane&15) (N index)
__global__ void k_pack(const unsigned short* __restrict__ W1c,
                       unsigned short* __restrict__ Mfrag) {
    const int g = blockIdx.x * 256 + threadIdx.x;       // < 1,081,344 exactly
    const int lane = g & 63;
    const int rec = g >> 6;                             // < 16896 = 64*11*24
    const int nf = rec % NFR;
    const int rec2 = rec / NFR;
    const int kc = rec2 % KCHK;
    const int e = rec2 / KCHK;
    const int i = nf * 16 + (lane & 15);
    const int jb = kc * 32 + ((lane >> 4) << 3);
    const unsigned short* wrow = W1c + (size_t)e * NF;

    __attribute__((aligned(16))) unsigned short v[8];
    #pragma unroll
    for (int r = 0; r < 8; ++r) {
        int j = jb + r;
        unsigned short out = 0;
        if (i <= j && j <= 320) {
            if (j == 320) {
                out = (i == 320) ? wrow[0] : wrow[1 + i];
            } else {
                int idx = 321 + i * 320 - ((i * (i - 1)) >> 1) + (j - i);
                out = wrow[idx];
            }
        }
        v[r] = out;
    }
    *(short8*)(Mfrag + (size_t)g * 8) = *(short8*)v;
}

// ---- k_main: block = (tile, e-pair). C = D' U_e, h = rowdot(C, D') ----
__global__ __launch_bounds__(1024, 1) void k_main(const float* __restrict__ x,
                                                  const unsigned short* __restrict__ Mfrag,
                                                  float* __restrict__ hbuf) {
    __shared__ unsigned short At[MT2 * (ATS / 2)];  // 96KB swizzled bf16
    __shared__ float xw[64 * XWS];                  // [e][r], stride 133
    __shared__ float hpart[2][8][64];

    const int tid = threadIdx.x;
    const int bid = blockIdx.x;                 // 256 blocks = 1/CU
    const int tile = bid >> 5;                  // 0..7
    const int ep = bid & 31;                    // XCD = ep%8
    const int e0 = ep * 2;
    const int tok0 = tile * MT2;
    const int b = tile >> 2, s0 = (tile & 3) * MT2;

    // stage xw[e][r] = x[b][s0-4+r][e], r in [0,132)
    #pragma unroll 1
    for (int idx = tid; idx < 132 * 64; idx += 1024) {
        int r = idx >> 6, ee = idx & 63;
        int s = s0 - 4 + r;
        xw[ee * XWS + r] = (s >= 0) ? x[((b << 9) + s) * 64 + ee] : 0.f;
    }
    __syncthreads();

    // build A-tile: At[t][j] = bf16(d'[t][j]), rows 384 shorts, swizzled
    char* Atb = (char*)At;
    #pragma unroll 1
    for (int rec = tid; rec < MT2 * 48; rec += 1024) {
        int t = rec / 48, jr = rec - t * 48;
        int j0 = jr * 8;
        __attribute__((aligned(16))) unsigned short hv[8];
        #pragma unroll
        for (int r = 0; r < 8; ++r) {
            int j = j0 + r;
            float v;
            if (j < 320) { int e5 = j / 5, k = j - e5 * 5; v = xw[e5 * XWS + t + k]; }
            else v = (j == 320) ? 1.0f : 0.f;
            hv[r] = f2bf(v);
        }
        *(short8*)(Atb + t * ATS + ((j0 * 2) ^ ((t & 7) << 4))) = *(short8*)hv;
    }
    __syncthreads();

    const int lane = tid & 63, wv = tid >> 6;   // 16 waves
    const int wm = wv >> 3, wn = wv & 7;        // M-half, N-slice
    const int nf0 = wn * 3;                     // uniform 3 frags per wave
    const int arow = wm * 64 + (lane & 15);
    const int aslot = (lane >> 4) << 4;

    // contraction d-operand bases (i per q, read from xw)
    int ibase[3]; float isel1[3], isel0[3];
    #pragma unroll
    for (int q = 0; q < 3; ++q) {
        int i = (nf0 + q) * 16 + (lane & 15);
        int ic = (i < 320) ? i : 0;
        ibase[q] = (ic / 5) * XWS + (ic % 5);
        isel1[q] = (i < 320) ? 1.f : 0.f;
        isel0[q] = (i == 320) ? 1.f : 0.f;
    }

    #pragma unroll 1
    for (int eo = 0; eo < 2; ++eo) {
        const unsigned short* Bbase = Mfrag + (size_t)(e0 + eo) * (KPAD * NPAD);

        f32x4 acc[4][3];
        #pragma unroll
        for (int mf = 0; mf < 4; ++mf)
            #pragma unroll
            for (int q = 0; q < 3; ++q) acc[mf][q] = f32x4{0.f,0.f,0.f,0.f};

        short8 B0[3], B1[3];

#define BLD(DST, KCV)                                                              \
    do { if ((KCV) < KCHK) {                                                       \
        _Pragma("unroll")                                                          \
        for (int q = 0; q < 3; ++q)                                                \
            DST[q] = *(const short8*)(Bbase +                                      \
                ((size_t)(((KCV) * NFR + nf0 + q) * 64 + lane)) * 8);              \
    } } while (0)

#define STEP(KCV, CUR)                                                             \
    do {                                                                           \
        short8 Af[4];                                                              \
        _Pragma("unroll")                                                          \
        for (int mf = 0; mf < 4; ++mf) {                                           \
            int t = arow + mf * 16;                                                \
            int jb = (KCV) * 64 + aslot;                                           \
            Af[mf] = *(const short8*)(Atb + t * ATS + (jb ^ ((t & 7) << 4)));      \
        }                                                                          \
        __builtin_amdgcn_s_setprio(1);                                             \
        _Pragma("unroll")                                                          \
        for (int mf = 0; mf < 4; ++mf) {                                           \
            _Pragma("unroll")                                                      \
            for (int q = 0; q < 3; ++q)                                            \
                acc[mf][q] = __builtin_amdgcn_mfma_f32_16x16x32_bf16(              \
                    Af[mf], CUR[q], acc[mf][q], 0, 0, 0);                          \
        }                                                                          \
        __builtin_amdgcn_s_setprio(0);                                             \
    } while (0)

        BLD(B0, 0);
        BLD(B1, 1);
        #pragma unroll 1
        for (int kc = 0; kc < KCHK - 1; kc += 2) {
            STEP(kc, B0);
            BLD(B0, kc + 2);        // prefetch: B0 dead after its MFMAs
            STEP(kc + 1, B1);
            BLD(B1, kc + 3);
        }
        STEP(KCHK - 1, B0);         // kc=10 (loaded in last iteration)
#undef STEP
#undef BLD

        // contraction: s[mf][r] = sum_i C[t][i]*d'[t][i]; d' read from xw
        float s[4][4];
        #pragma unroll
        for (int mf = 0; mf < 4; ++mf)
            #pragma unroll
            for (int r = 0; r < 4; ++r) s[mf][r] = 0.f;

        #pragma unroll
        for (int q = 0; q < 3; ++q) {
            #pragma unroll
            for (int mf = 0; mf < 4; ++mf)
                #pragma unroll
                for (int r = 0; r < 4; ++r) {
                    int t = wm * 64 + mf * 16 + ((lane >> 4) << 2) + r;
                    float dv = isel1[q] * xw[ibase[q] + t] + isel0[q];
                    s[mf][r] += acc[mf][q][r] * dv;
                }
        }
        #pragma unroll
        for (int mf = 0; mf < 4; ++mf)
            #pragma unroll
            for (int r = 0; r < 4; ++r) {
                float v = s[mf][r];
                v += __shfl_xor(v, 1);
                v += __shfl_xor(v, 2);
                v += __shfl_xor(v, 4);
                v += __shfl_xor(v, 8);
                s[mf][r] = v;
            }
        if ((lane & 15) == 0) {
            #pragma unroll
            for (int mf = 0; mf < 4; ++mf)
                #pragma unroll
                for (int r = 0; r < 4; ++r)
                    hpart[wm][wn][mf * 16 + ((lane >> 4) << 2) + r] = s[mf][r];
        }
        __syncthreads();
        if (tid < 128) {
            int wmx = tid >> 6, tl = tid & 63;
            float v = 0.f;
            #pragma unroll
            for (int w = 0; w < 8; ++w) v += hpart[wmx][w][tl];
            hbuf[(size_t)(tok0 + wmx * 64 + tl) * 64 + (e0 + eo)] = v;
        }
        __syncthreads();   // hpart readers done before next eo overwrites
    }
}

// ---- epilogue: out = GELU(hbuf + b1) @ W2 + b2 ----
__global__ void k_epi(const float* __restrict__ hbuf, const float* __restrict__ b1,
                      const float* __restrict__ W2, const float* __restrict__ b2,
                      float* __restrict__ out) {
    __shared__ float h[4 * 64];
    int tid = threadIdx.x;
    int t = tid >> 6, e = tid & 63;
    int token = blockIdx.x * 4 + t;
    float pre = hbuf[token * 64 + e] + b1[e];
    float hv = 0.5f * pre * (1.0f + erff(pre * 0.70710678118654752f));  // exact GELU
    h[t * 64 + e] = hv;
    __syncthreads();
    float s = b2[e];
    #pragma unroll 8
    for (int ee = 0; ee < 64; ++ee)
        s += h[t * 64 + ee] * W2[ee * 64 + e];
    out[token * 64 + e] = s;
}

extern "C" void kernel_launch(void* const* d_in, const int* in_sizes, int n_in,
                              void* d_out, int out_size, void* d_ws, size_t ws_size,
                              hipStream_t stream) {
    const float* x  = (const float*)d_in[0];
    const float* W1 = (const float*)d_in[1];
    const float* b1 = (const float*)d_in[2];
    const float* W2 = (const float*)d_in[3];
    const float* b2 = (const float*)d_in[4];
    float* out = (float*)d_out;

    unsigned short* W1c   = (unsigned short*)d_ws;
    unsigned short* Mfrag = (unsigned short*)((char*)d_ws + W1C_BYTES);
    float* hbuf           = (float*)((char*)d_ws + HBUF_OFF);

    k_t<<<(NF + 63) / 64, 256, 0, stream>>>(W1, W1c);
    k_pack<<<4224, 256, 0, stream>>>(W1c, Mfrag);          // 1,081,344 threads
    k_main<<<256, 1024, 0, stream>>>(x, Mfrag, hbuf);
    k_epi<<<256, 256, 0, stream>>>(hbuf, b1, W2, b2, out);
}